// Round 22
// baseline (179.102 us; speedup 1.0000x reference)
//
#include <hip/hip_runtime.h>

#define CC 32
#define DIM 24
#define SP (DIM*DIM*DIM)     // 13824
#define NPTS 27
#define M3 81
#define OUTC 64
#define BATCH 2
#define CN (CC*NPTS)         // 864 = K

#define VBB 12               // voxels per block, kernel B
#define NV (NPTS*VBB)        // 324 sample points per block
#define CPAD 896             // padded col row (XOR swizzle overflow space)
#define MP 84                // padded M for offset GEMM (81 -> 84)
#define HROW 26              // halo k-pitch
#define HALOF (CC*3*4*HROW)  // 9984 floats = 39936 B

typedef __attribute__((ext_vector_type(8))) short short8;
typedef __attribute__((ext_vector_type(4))) float f32x4;

__device__ __forceinline__ unsigned short f2bf(float f) {
    unsigned u = __builtin_bit_cast(unsigned, f);
    return (unsigned short)((u + 0x7FFFu + ((u >> 16) & 1u)) >> 16);
}

// ---------------- Kernel T1: weight prep ----------------
// p_wTP[k*84+m] = p_w[m*864+k] (fp32, zero-padded m 81..83)
// conv_wbf[o*864 + n*32+c] = bf16(conv_w[o*864 + c*27+n])   (K-permuted)
__global__ __launch_bounds__(256)
void prep_w_kernel(const float* __restrict__ p_w,
                   const float* __restrict__ conv_w,
                   float* __restrict__ p_wTP,
                   unsigned short* __restrict__ conv_wbf) {
    int id = blockIdx.x * 256 + threadIdx.x;
    if (id < CN * MP) {
        int k = id / MP, m = id % MP;
        p_wTP[id] = (m < M3) ? p_w[(size_t)m * CN + k] : 0.f;
    }
    if (id < CN * OUTC) {
        int o = id / CN, kp = id % CN;
        int n = kp >> 5, c = kp & 31;
        conv_wbf[id] = f2bf(conv_w[(size_t)o * CN + c * NPTS + n]);
    }
}

// ---------------- Kernel T2: x -> x_t[b][sp][c] (bf16, channel-minor) -------
__global__ __launch_bounds__(256)
void transpose_x_kernel(const float* __restrict__ x,
                        unsigned short* __restrict__ x_t) {
    __shared__ float tile[CC][65];
    int b = blockIdx.x / 216;
    int sp0 = (blockIdx.x % 216) * 64;
    const float* xb = x + (size_t)b * CC * SP;
    for (int it = threadIdx.x; it < CC * 64; it += 256) {
        int c = it >> 6, s = it & 63;
        tile[c][s] = xb[(size_t)c * SP + sp0 + s];
    }
    __syncthreads();
    unsigned short* xtb = x_t + (size_t)b * SP * CC;
    for (int it = threadIdx.x; it < CC * 64; it += 256) {
        int s = it >> 5, c = it & 31;
        xtb[(size_t)(sp0 + s) * CC + c] = f2bf(tile[c][s]);
    }
}

// ---------------- Kernel A: offset conv, scalar-weight broadcast form -------
// Block = (b, i, j-pair): 48 voxels, grid 576, 256 threads.
// Wave w owns m in [21w, 21w+21) over ALL 864 k (no K-split, no reduce).
// Lane = voxel (48 of 64 active). Weight addresses are wave-uniform
// (readfirstlane on wave id) -> backend emits s_load: weights ride the
// SCALAR pipe, zero vector-issue cost, and the K-loop has NO VMEM --
// the r5-r20 vector-weight-latency wall is bypassed, not hidden.
// Per k: 1 LDS read (compiler-merged ds_read2) + 21 v_fma (SGPR operand).
__global__ __launch_bounds__(256, 4)
void offset_gemm_kernel(const float* __restrict__ x,
                        const float* __restrict__ p_wTP,
                        const float* __restrict__ p_b,
                        float* __restrict__ offset) {
    __shared__ float halo[HALOF];            // 39936 B

    int bid = blockIdx.x;                    // 576 = 2*24*12
    int jp = bid % 12;
    int i  = (bid / 12) % 24;
    int b  = bid / 288;
    int j0 = jp * 2;
    int sp0 = i * 576 + j0 * 24;
    int t = threadIdx.x;

    // --- halo: halo[((c*3+di)*4+jq)*26 + u] = x[b][c][i+di-1][j0-1+jq][u-1]
    for (int it = t; it < HALOF; it += 256) {
        int rh = it / HROW, u = it - rh * HROW;
        int c = rh / 12, r2 = rh - c * 12;
        int di = r2 >> 2, jq = r2 & 3;
        int ii = i + di - 1, jj = j0 - 1 + jq, kk = u - 1;
        bool v = ((unsigned)ii < (unsigned)DIM) && ((unsigned)jj < (unsigned)DIM) &&
                 ((unsigned)kk < (unsigned)DIM);
        halo[it] =
            v ? x[((size_t)(b * CC + c) * SP) + ii * 576 + jj * 24 + kk] : 0.f;
    }
    __syncthreads();

    int l = t & 63;
    int wu = __builtin_amdgcn_readfirstlane(t >> 6);  // wave id, forced SGPR
    bool act = (l < 48);
    int vl = act ? l : 47;                   // clamp: idle lanes read in-range
    int jrow = vl / 24, kv = vl - jrow * 24;
    int lane_base = jrow * HROW + kv;

    float acc[21];
    #pragma unroll
    for (int mm = 0; mm < 21; ++mm) acc[mm] = 0.f;

    const float* wbase = p_wTP + 21 * wu;    // wave-uniform

    for (int c = 0; c < CC; ++c) {
        const float* hb = halo + c * (3 * 4 * HROW) + lane_base;
        const float* wc = wbase + (size_t)(c * 27) * MP;
        #pragma unroll
        for (int dij = 0; dij < 9; ++dij) {
            int di = dij / 3, dj = dij % 3;
            const float* hrow = hb + (di * 4 + dj) * HROW;
            #pragma unroll
            for (int dk = 0; dk < 3; ++dk) {
                float xv = hrow[dk];                       // LDS, imm offset
                const float* wr = wc + (size_t)(dij * 3 + dk) * MP;  // uniform
                #pragma unroll
                for (int mm = 0; mm < 21; ++mm)
                    acc[mm] += wr[mm] * xv;                // v_fma, SGPR src
            }
        }
    }

    // --- store: lane v writes its 21 m's (bias added; pads m>=81 dropped) ---
    if (act) {
        int spv = sp0 + jrow * 24 + kv;
        #pragma unroll
        for (int mm = 0; mm < 21; ++mm) {
            int m = 21 * wu + mm;
            if (m < M3)
                offset[((size_t)(b * M3 + m)) * SP + spv] = acc[mm] + p_b[m];
        }
    }
}

// ------------- Kernel B: sample + project, 4-lane-per-point gather ----------
// Phase 2: 4 lanes per sample point, each owning an 8-channel slice ->
// contiguous quarters of each 64B corner line (16 L1 lines/wave-load vs 64).
// Measured ~39us (r15). VGPR floor >=64 at (256,4) (r12: 48 VGPR = +50us).
__global__ __launch_bounds__(256, 4)
void sample_gemm_kernel(const unsigned short* __restrict__ x_t,
                        const float* __restrict__ offset,
                        const unsigned short* __restrict__ conv_wbf,
                        float* __restrict__ out,     // [2, 64, SP]
                        float* __restrict__ p_out) { // [2, SP, 81]
    // region: col[12][896] bf16 (21504 B) then s_corner[8][324] u32 (10368 B)
    __shared__ __align__(16) unsigned char region[VBB * CPAD * 2 + 8 * NV * 4];
    unsigned short* col = (unsigned short*)region;
    unsigned* s_corner = (unsigned*)(region + VBB * CPAD * 2);

    int bid = blockIdx.x;                    // 2304 = 2*24*24*2
    int r = bid & 1;
    int j = (bid >> 1) % 24;
    int i = ((bid >> 1) / 24) % 24;
    int b = bid / 1152;
    int k0 = r * VBB;
    int sp0 = i * 576 + j * 24 + k0;
    int t = threadIdx.x;

    const unsigned short* xtb = x_t + (size_t)b * SP * CC;

    // --- phase 1: corners + p_out ---
    for (int it = t; it < NV; it += 256) {
        int v = it % VBB, n = it / VBB;
        int sp = sp0 + v;
        int k = k0 + v;

        int pnx = n / 9 - 1, pny = (n / 3) % 3 - 1, pnz = n % 3 - 1;
        float p0a[3] = { (float)(i + 1 + pnx),
                         (float)(j + 1 + pny),
                         (float)(k + 1 + pnz) };
        int ql[3], qh[3];
        float wl[3], wh[3];
        #pragma unroll
        for (int ax = 0; ax < 3; ++ax) {
            int m = ax * NPTS + n;
            float p = p0a[ax] + offset[((size_t)(b * M3 + m)) * SP + sp];
            float f = floorf(p);
            int qlo = (int)fminf(fmaxf(f,       0.f), 25.f);
            int qhi = (int)fminf(fmaxf(f + 1.f, 0.f), 25.f);
            bool oob = (p < 1.f) || (p > 24.f);
            float pa = oob ? f : p;
            float pm = fminf(fmaxf(pa, 0.f), 25.f);
            ql[ax] = qlo; qh[ax] = qhi;
            wl[ax] = 1.f + ((float)qlo - pm);
            wh[ax] = 1.f - ((float)qhi - pm);
            p_out[((size_t)(b * SP + sp)) * M3 + m] = pm;
        }

        #pragma unroll
        for (int cr = 0; cr < 8; ++cr) {
            int ii = ((cr & 4) ? qh[0] : ql[0]) - 1;
            int jj = ((cr & 2) ? qh[1] : ql[1]) - 1;
            int kk = ((cr & 1) ? qh[2] : ql[2]) - 1;
            bool valid = ((unsigned)ii < (unsigned)DIM) &&
                         ((unsigned)jj < (unsigned)DIM) &&
                         ((unsigned)kk < (unsigned)DIM);
            float cw = ((cr & 4) ? wh[0] : wl[0]) *
                       ((cr & 2) ? wh[1] : wl[1]) *
                       ((cr & 1) ? wh[2] : wl[2]);
            unsigned idx = (unsigned)(ii * 576 + jj * 24 + kk);
            s_corner[cr * NV + it] =
                valid ? ((idx << 16) | (unsigned)f2bf(cw)) : 0u;
        }
    }
    __syncthreads();

    // --- phase 2: gather; 4 lanes per item, lane owns 8-channel slice q ---
    for (int task = t; task < NV * 4; task += 256) {
        int item = task >> 2, q = task & 3;
        int v = item % VBB, n = item / VBB;

        const unsigned short* xq = xtb + q * 8;
        float acc[8];
        #pragma unroll
        for (int e = 0; e < 8; ++e) acc[e] = 0.f;

        #pragma unroll
        for (int cr = 0; cr < 8; ++cr) {
            unsigned u = s_corner[cr * NV + item];
            float wc = __builtin_bit_cast(float, u << 16);
            const unsigned* s = (const unsigned*)(xq + (size_t)(u >> 16) * CC);
            #pragma unroll
            for (int q2 = 0; q2 < 4; ++q2) {
                unsigned uu = s[q2];
                acc[2 * q2]     += wc * __builtin_bit_cast(float, uu << 16);
                acc[2 * q2 + 1] += wc * __builtin_bit_cast(float, uu & 0xFFFF0000u);
            }
        }

        short8 pk;
        #pragma unroll
        for (int e = 0; e < 8; ++e)
            pk[e] = (short)f2bf(acc[e]);
        int sv = (v & 7) << 3;
        *(short8*)&col[v * CPAD + ((n * 32 + q * 8) ^ sv)] = pk;
    }
    __syncthreads();

    // --- phase 3: MFMA GEMM 64 x 864 @ 864 x 12 ---
    {
        int mt = t >> 6;                      // wave -> M tile (16 rows)
        int l = t & 63;
        int lr = l & 15;                      // A row / B col (voxel)
        int g = l >> 4;
        int sv = (lr & 7) << 3;

        const short8* ap =
            (const short8*)(conv_wbf + ((size_t)(mt * 16 + lr)) * CN + g * 8);
        const unsigned short* bp = col + lr * CPAD;

        f32x4 acc = {0.f, 0.f, 0.f, 0.f};
        #pragma unroll 3
        for (int kb = 0; kb < CN / 32; ++kb) {
            short8 a = ap[kb * 4];
            short8 bb = *(const short8*)&bp[(kb * 32 + g * 8) ^ sv];
            acc = __builtin_amdgcn_mfma_f32_16x16x32_bf16(a, bb, acc, 0, 0, 0);
        }
        if (lr < VBB) {
            float* op = out + ((size_t)(b * OUTC + mt * 16 + g * 4)) * SP + sp0 + lr;
            #pragma unroll
            for (int rr = 0; rr < 4; ++rr)
                op[(size_t)rr * SP] = acc[rr];
        }
    }
}

extern "C" void kernel_launch(void* const* d_in, const int* in_sizes, int n_in,
                              void* d_out, int out_size, void* d_ws, size_t ws_size,
                              hipStream_t stream) {
    const float* x      = (const float*)d_in[0];
    const float* p_w    = (const float*)d_in[1];
    const float* p_b    = (const float*)d_in[2];
    const float* conv_w = (const float*)d_in[3];

    float* out_all = (float*)d_out;
    float* out_main = out_all;                               // [2,64,13824]
    float* p_out    = out_all + (size_t)BATCH * OUTC * SP;   // [2,13824,81]

    float* offset          = (float*)d_ws;                   // [2,81,13824]
    float* p_wTP           = offset + (size_t)BATCH * M3 * SP;
    unsigned short* conv_wbf = (unsigned short*)(p_wTP + (size_t)CN * MP);
    unsigned short* x_t    = conv_wbf + (size_t)CN * OUTC;   // [2,13824,32] bf16

    {
        int total = CN * MP;                                 // 72576 covers both
        prep_w_kernel<<<(total + 255) / 256, 256, 0, stream>>>(p_w, conv_w,
                                                               p_wTP, conv_wbf);
    }
    {
        int blocks = BATCH * (SP / 64);                      // 432
        transpose_x_kernel<<<blocks, 256, 0, stream>>>(x, x_t);
    }
    {
        int blocks = BATCH * 24 * 12;                        // 576
        offset_gemm_kernel<<<blocks, 256, 0, stream>>>(x, p_wTP, p_b, offset);
    }
    {
        int blocks = BATCH * 24 * 24 * 2;                    // 2304
        sample_gemm_kernel<<<blocks, 256, 0, stream>>>(x_t, offset, conv_wbf,
                                                       out_main, p_out);
    }
}

// Round 23
// 116.008 us; speedup vs baseline: 1.5439x; 1.5439x over previous
//
#include <hip/hip_runtime.h>

#define CC 32
#define DIM 24
#define SP (DIM*DIM*DIM)     // 13824
#define NPTS 27
#define M3 81
#define OUTC 64
#define BATCH 2
#define CN (CC*NPTS)         // 864 = K

#define VBB 12               // voxels per block, kernel B
#define NV (NPTS*VBB)        // 324 sample points per block
#define CPAD 896             // padded col row (XOR swizzle overflow space)
#define MP 84                // padded M for offset GEMM (81 -> 84)
#define XR 26                // x-halo row pitch, fully packed

typedef __attribute__((ext_vector_type(8))) short short8;
typedef __attribute__((ext_vector_type(4))) float f32x4;

__device__ __forceinline__ unsigned short f2bf(float f) {
    unsigned u = __builtin_bit_cast(unsigned, f);
    return (unsigned short)((u + 0x7FFFu + ((u >> 16) & 1u)) >> 16);
}

// ---------------- Kernel T1: weight prep ----------------
__global__ __launch_bounds__(256)
void prep_w_kernel(const float* __restrict__ p_w,
                   const float* __restrict__ conv_w,
                   float* __restrict__ p_wTP,
                   unsigned short* __restrict__ conv_wbf) {
    int id = blockIdx.x * 256 + threadIdx.x;
    if (id < CN * MP) {
        int k = id / MP, m = id % MP;
        p_wTP[id] = (m < M3) ? p_w[(size_t)m * CN + k] : 0.f;
    }
    if (id < CN * OUTC) {
        int o = id / CN, kp = id % CN;
        int n = kp >> 5, c = kp & 31;
        conv_wbf[id] = f2bf(conv_w[(size_t)o * CN + c * NPTS + n]);
    }
}

// ---------------- Kernel T2: x -> x_t[b][sp][c] (bf16, channel-minor) -------
__global__ __launch_bounds__(256)
void transpose_x_kernel(const float* __restrict__ x,
                        unsigned short* __restrict__ x_t) {
    __shared__ float tile[CC][65];
    int b = blockIdx.x / 216;
    int sp0 = (blockIdx.x % 216) * 64;
    const float* xb = x + (size_t)b * CC * SP;
    for (int it = threadIdx.x; it < CC * 64; it += 256) {
        int c = it >> 6, s = it & 63;
        tile[c][s] = xb[(size_t)c * SP + sp0 + s];
    }
    __syncthreads();
    unsigned short* xtb = x_t + (size_t)b * SP * CC;
    for (int it = threadIdx.x; it < CC * 64; it += 256) {
        int s = it >> 5, c = it & 31;
        xtb[(size_t)(sp0 + s) * CC + c] = f2bf(tile[c][s]);
    }
}

// ---------------- Kernel A: offset conv (converged optimum: 72us) -----------
// Block = (b,i,j) full k-row (24 voxels), grid 1152. LDS = packed x halo
// [288][26] fp32 = 29952 B -> 5 blocks/CU. 4-wave K-split (8 ch/wave);
// lane tile 4m x 8v (32 FMA per weight float4). Minimum of 10 structural
// variants + 7 prefetch mechanisms (r5-r22). Remaining gap to the 26us
// FMA floor is the compiler's sink-at-use weight stream: C-prefetch
// defeated x4, asm racy x2, global_load_lds slower, s_load shares
// lgkmcnt with LDS and serializes (r22: 135us).
__global__ __launch_bounds__(256, 5)
void offset_gemm_kernel(const float* __restrict__ x,
                        const float* __restrict__ p_wTP,
                        const float* __restrict__ p_b,
                        float* __restrict__ offset) {
    __shared__ float lds[288 * XR];          // 29952 B

    int bid = blockIdx.x;                    // 1152 = 2*24*24
    int j = bid % 24;
    int i = (bid / 24) % 24;
    int b = bid / 576;
    int sp0 = i * 576 + j * 24;
    int t = threadIdx.x;

    for (int it = t; it < 288 * 26; it += 256) {
        int row = it / 26, u = it % 26;
        int c = row / 9, dij = row % 9;
        int di = dij / 3, dj = dij % 3;
        int ii = i + di - 1, jj = j + dj - 1, kk = u - 1;
        bool v = ((unsigned)ii < (unsigned)DIM) && ((unsigned)jj < (unsigned)DIM) &&
                 ((unsigned)kk < (unsigned)DIM);
        lds[it] =
            v ? x[((size_t)(b * CC + c) * SP) + ii * 576 + jj * 24 + kk] : 0.f;
    }
    __syncthreads();

    int w = t >> 6, l = t & 63;
    int mt = l / 3, vt = l % 3;
    bool act = (l < 63);
    if (mt > 20) mt = 20;                    // lane 63: duplicate, store-guarded

    float acc[4][8];
    #pragma unroll
    for (int a = 0; a < 4; ++a)
        #pragma unroll
        for (int e = 0; e < 8; ++e) acc[a][e] = 0.f;

    const float* wbase = p_wTP + (size_t)(w * 216) * MP + mt * 4;
    const float* xbase = lds + (w * 72) * XR + vt * 8;

    float4 pwA[3], pwB[3];
    #pragma unroll
    for (int dk = 0; dk < 3; ++dk)
        pwA[dk] = *(const float4*)(wbase + (size_t)dk * MP);

    #define FMA_BODY(PW, CDIJ)                                              \
        do {                                                                \
            const float* xr = xbase + (CDIJ) * XR;                          \
            float2 x0 = *(const float2*)(xr);                               \
            float2 x1 = *(const float2*)(xr + 2);                           \
            float2 x2 = *(const float2*)(xr + 4);                           \
            float2 x3 = *(const float2*)(xr + 6);                           \
            float2 x4 = *(const float2*)(xr + 8);                           \
            float xv[10] = { x0.x, x0.y, x1.x, x1.y, x2.x, x2.y,            \
                             x3.x, x3.y, x4.x, x4.y };                      \
            _Pragma("unroll")                                               \
            for (int dk = 0; dk < 3; ++dk) {                                \
                float4 wv = PW[dk];                                         \
                _Pragma("unroll")                                           \
                for (int e = 0; e < 8; ++e) {                               \
                    float xvv = xv[dk + e];                                 \
                    acc[0][e] += wv.x * xvv;                                \
                    acc[1][e] += wv.y * xvv;                                \
                    acc[2][e] += wv.z * xvv;                                \
                    acc[3][e] += wv.w * xvv;                                \
                }                                                           \
            }                                                               \
        } while (0)

    for (int cdij = 0; cdij < 72; cdij += 2) {
        {   // even: issue prefetch of cdij+1 into pwB, pin, compute cdij
            const float* wn = wbase + (size_t)((cdij + 1) * 3) * MP;
            #pragma unroll
            for (int dk = 0; dk < 3; ++dk)
                pwB[dk] = *(const float4*)(wn + (size_t)dk * MP);
            __builtin_amdgcn_sched_barrier(0);
            FMA_BODY(pwA, cdij);
        }
        {   // odd: prefetch cdij+2 into pwA; tail overreads land in the
            // adjacent conv_wbf ws region (valid memory, values unused).
            const float* wn = wbase + (size_t)((cdij + 2) * 3) * MP;
            #pragma unroll
            for (int dk = 0; dk < 3; ++dk)
                pwA[dk] = *(const float4*)(wn + (size_t)dk * MP);
            __builtin_amdgcn_sched_barrier(0);
            FMA_BODY(pwB, cdij + 1);
        }
    }
    #undef FMA_BODY
    __syncthreads();

    float* part = lds;                        // 2*84*24*4 = 16128 B
    if (act && w < 2) {
        #pragma unroll
        for (int a = 0; a < 4; ++a) {
            #pragma unroll
            for (int e2 = 0; e2 < 2; ++e2) {
                float4 pv = make_float4(acc[a][e2 * 4], acc[a][e2 * 4 + 1],
                                        acc[a][e2 * 4 + 2], acc[a][e2 * 4 + 3]);
                *(float4*)&part[((w * MP) + mt * 4 + a) * 24 + vt * 8 + e2 * 4] = pv;
            }
        }
    }
    __syncthreads();
    if (act && w >= 2) {
        #pragma unroll
        for (int a = 0; a < 4; ++a) {
            #pragma unroll
            for (int e2 = 0; e2 < 2; ++e2) {
                float* dst = &part[(((w - 2) * MP) + mt * 4 + a) * 24 + vt * 8 + e2 * 4];
                float4 pv = *(const float4*)dst;
                pv.x += acc[a][e2 * 4];     pv.y += acc[a][e2 * 4 + 1];
                pv.z += acc[a][e2 * 4 + 2]; pv.w += acc[a][e2 * 4 + 3];
                *(float4*)dst = pv;
            }
        }
    }
    __syncthreads();

    for (int it = t; it < M3 * 6; it += 256) {
        int m = it / 6, vq = it % 6;
        float4 p0 = *(const float4*)&part[(m) * 24 + vq * 4];
        float4 p1 = *(const float4*)&part[(MP + m) * 24 + vq * 4];
        float bias = p_b[m];
        float4 s = make_float4(p0.x + p1.x + bias, p0.y + p1.y + bias,
                               p0.z + p1.z + bias, p0.w + p1.w + bias);
        *(float4*)&offset[((size_t)(b * M3 + m)) * SP + sp0 + vq * 4] = s;
    }
}

// ------------- Kernel B: sample + project, 4-lane-per-point gather ----------
// Phase 2: 4 lanes per sample point, each owning an 8-channel slice ->
// contiguous quarters of each 64B corner line (16 L1 lines/wave-load vs 64).
// Measured ~39us (r15). VGPR floor >=64 at (256,4) (r12: 48 VGPR = +50us).
__global__ __launch_bounds__(256, 4)
void sample_gemm_kernel(const unsigned short* __restrict__ x_t,
                        const float* __restrict__ offset,
                        const unsigned short* __restrict__ conv_wbf,
                        float* __restrict__ out,     // [2, 64, SP]
                        float* __restrict__ p_out) { // [2, SP, 81]
    // region: col[12][896] bf16 (21504 B) then s_corner[8][324] u32 (10368 B)
    __shared__ __align__(16) unsigned char region[VBB * CPAD * 2 + 8 * NV * 4];
    unsigned short* col = (unsigned short*)region;
    unsigned* s_corner = (unsigned*)(region + VBB * CPAD * 2);

    int bid = blockIdx.x;                    // 2304 = 2*24*24*2
    int r = bid & 1;
    int j = (bid >> 1) % 24;
    int i = ((bid >> 1) / 24) % 24;
    int b = bid / 1152;
    int k0 = r * VBB;
    int sp0 = i * 576 + j * 24 + k0;
    int t = threadIdx.x;

    const unsigned short* xtb = x_t + (size_t)b * SP * CC;

    // --- phase 1: corners + p_out ---
    for (int it = t; it < NV; it += 256) {
        int v = it % VBB, n = it / VBB;
        int sp = sp0 + v;
        int k = k0 + v;

        int pnx = n / 9 - 1, pny = (n / 3) % 3 - 1, pnz = n % 3 - 1;
        float p0a[3] = { (float)(i + 1 + pnx),
                         (float)(j + 1 + pny),
                         (float)(k + 1 + pnz) };
        int ql[3], qh[3];
        float wl[3], wh[3];
        #pragma unroll
        for (int ax = 0; ax < 3; ++ax) {
            int m = ax * NPTS + n;
            float p = p0a[ax] + offset[((size_t)(b * M3 + m)) * SP + sp];
            float f = floorf(p);
            int qlo = (int)fminf(fmaxf(f,       0.f), 25.f);
            int qhi = (int)fminf(fmaxf(f + 1.f, 0.f), 25.f);
            bool oob = (p < 1.f) || (p > 24.f);
            float pa = oob ? f : p;
            float pm = fminf(fmaxf(pa, 0.f), 25.f);
            ql[ax] = qlo; qh[ax] = qhi;
            wl[ax] = 1.f + ((float)qlo - pm);
            wh[ax] = 1.f - ((float)qhi - pm);
            p_out[((size_t)(b * SP + sp)) * M3 + m] = pm;
        }

        #pragma unroll
        for (int cr = 0; cr < 8; ++cr) {
            int ii = ((cr & 4) ? qh[0] : ql[0]) - 1;
            int jj = ((cr & 2) ? qh[1] : ql[1]) - 1;
            int kk = ((cr & 1) ? qh[2] : ql[2]) - 1;
            bool valid = ((unsigned)ii < (unsigned)DIM) &&
                         ((unsigned)jj < (unsigned)DIM) &&
                         ((unsigned)kk < (unsigned)DIM);
            float cw = ((cr & 4) ? wh[0] : wl[0]) *
                       ((cr & 2) ? wh[1] : wl[1]) *
                       ((cr & 1) ? wh[2] : wl[2]);
            unsigned idx = (unsigned)(ii * 576 + jj * 24 + kk);
            s_corner[cr * NV + it] =
                valid ? ((idx << 16) | (unsigned)f2bf(cw)) : 0u;
        }
    }
    __syncthreads();

    // --- phase 2: gather; 4 lanes per item, lane owns 8-channel slice q ---
    for (int task = t; task < NV * 4; task += 256) {
        int item = task >> 2, q = task & 3;
        int v = item % VBB, n = item / VBB;

        const unsigned short* xq = xtb + q * 8;
        float acc[8];
        #pragma unroll
        for (int e = 0; e < 8; ++e) acc[e] = 0.f;

        #pragma unroll
        for (int cr = 0; cr < 8; ++cr) {
            unsigned u = s_corner[cr * NV + item];
            float wc = __builtin_bit_cast(float, u << 16);
            const unsigned* s = (const unsigned*)(xq + (size_t)(u >> 16) * CC);
            #pragma unroll
            for (int q2 = 0; q2 < 4; ++q2) {
                unsigned uu = s[q2];
                acc[2 * q2]     += wc * __builtin_bit_cast(float, uu << 16);
                acc[2 * q2 + 1] += wc * __builtin_bit_cast(float, uu & 0xFFFF0000u);
            }
        }

        short8 pk;
        #pragma unroll
        for (int e = 0; e < 8; ++e)
            pk[e] = (short)f2bf(acc[e]);
        int sv = (v & 7) << 3;
        *(short8*)&col[v * CPAD + ((n * 32 + q * 8) ^ sv)] = pk;
    }
    __syncthreads();

    // --- phase 3: MFMA GEMM 64 x 864 @ 864 x 12 ---
    {
        int mt = t >> 6;                      // wave -> M tile (16 rows)
        int l = t & 63;
        int lr = l & 15;                      // A row / B col (voxel)
        int g = l >> 4;
        int sv = (lr & 7) << 3;

        const short8* ap =
            (const short8*)(conv_wbf + ((size_t)(mt * 16 + lr)) * CN + g * 8);
        const unsigned short* bp = col + lr * CPAD;

        f32x4 acc = {0.f, 0.f, 0.f, 0.f};
        #pragma unroll 3
        for (int kb = 0; kb < CN / 32; ++kb) {
            short8 a = ap[kb * 4];
            short8 bb = *(const short8*)&bp[(kb * 32 + g * 8) ^ sv];
            acc = __builtin_amdgcn_mfma_f32_16x16x32_bf16(a, bb, acc, 0, 0, 0);
        }
        if (lr < VBB) {
            float* op = out + ((size_t)(b * OUTC + mt * 16 + g * 4)) * SP + sp0 + lr;
            #pragma unroll
            for (int rr = 0; rr < 4; ++rr)
                op[(size_t)rr * SP] = acc[rr];
        }
    }
}

extern "C" void kernel_launch(void* const* d_in, const int* in_sizes, int n_in,
                              void* d_out, int out_size, void* d_ws, size_t ws_size,
                              hipStream_t stream) {
    const float* x      = (const float*)d_in[0];
    const float* p_w    = (const float*)d_in[1];
    const float* p_b    = (const float*)d_in[2];
    const float* conv_w = (const float*)d_in[3];

    float* out_all = (float*)d_out;
    float* out_main = out_all;                               // [2,64,13824]
    float* p_out    = out_all + (size_t)BATCH * OUTC * SP;   // [2,13824,81]

    float* offset          = (float*)d_ws;                   // [2,81,13824]
    float* p_wTP           = offset + (size_t)BATCH * M3 * SP;
    unsigned short* conv_wbf = (unsigned short*)(p_wTP + (size_t)CN * MP);
    unsigned short* x_t    = conv_wbf + (size_t)CN * OUTC;   // [2,13824,32] bf16

    {
        int total = CN * MP;                                 // 72576 covers both
        prep_w_kernel<<<(total + 255) / 256, 256, 0, stream>>>(p_w, conv_w,
                                                               p_wTP, conv_wbf);
    }
    {
        int blocks = BATCH * (SP / 64);                      // 432
        transpose_x_kernel<<<blocks, 256, 0, stream>>>(x, x_t);
    }
    {
        int blocks = BATCH * 24 * 24;                        // 1152
        offset_gemm_kernel<<<blocks, 256, 0, stream>>>(x, p_wTP, p_b, offset);
    }
    {
        int blocks = BATCH * 24 * 24 * 2;                    // 2304
        sample_gemm_kernel<<<blocks, 256, 0, stream>>>(x_t, offset, conv_wbf,
                                                       out_main, p_out);
    }
}

// Round 24
// 112.225 us; speedup vs baseline: 1.5959x; 1.0337x over previous
//
#include <hip/hip_runtime.h>

#define CC 32
#define DIM 24
#define SP (DIM*DIM*DIM)     // 13824
#define NPTS 27
#define M3 81
#define OUTC 64
#define BATCH 2
#define CN (CC*NPTS)         // 864 = K

#define VBB 12               // voxels per block, kernel B
#define NV (NPTS*VBB)        // 324 sample points per block
#define CPAD 896             // padded col row (XOR swizzle overflow space)
#define MP 84                // padded M for offset GEMM (81 -> 84)
#define XR 26                // x-halo row pitch, fully packed

typedef __attribute__((ext_vector_type(8))) short short8;
typedef __attribute__((ext_vector_type(4))) float f32x4;

__device__ __forceinline__ unsigned short f2bf(float f) {
    unsigned u = __builtin_bit_cast(unsigned, f);
    return (unsigned short)((u + 0x7FFFu + ((u >> 16) & 1u)) >> 16);
}

// ---------------- Kernel T1: weight prep ----------------
__global__ __launch_bounds__(256)
void prep_w_kernel(const float* __restrict__ p_w,
                   const float* __restrict__ conv_w,
                   float* __restrict__ p_wTP,
                   unsigned short* __restrict__ conv_wbf) {
    int id = blockIdx.x * 256 + threadIdx.x;
    if (id < CN * MP) {
        int k = id / MP, m = id % MP;
        p_wTP[id] = (m < M3) ? p_w[(size_t)m * CN + k] : 0.f;
    }
    if (id < CN * OUTC) {
        int o = id / CN, kp = id % CN;
        int n = kp >> 5, c = kp & 31;
        conv_wbf[id] = f2bf(conv_w[(size_t)o * CN + c * NPTS + n]);
    }
}

// ---------------- Kernel A: offset conv + fused x_t emission ---------------
// Block = (b,i,j) full k-row (24 voxels), grid 1152. LDS = packed x halo
// [288][26] fp32 = 29952 B -> 5 blocks/CU. 4-wave K-split (8 ch/wave);
// lane tile 4m x 8v (32 FMA per weight float4). Converged minimum of 10
// structural variants + 7 prefetch mechanisms (r5-r22). NEW (r24): emits
// x_t (bf16 channel-minor) from the halo's center plane -- replaces the
// separate transpose_x kernel (halo[di=1,dj=1] of block (b,i,j) IS
// x[b][:,i,j,:], each voxel centered in exactly one block; the 768
// stores per block are one contiguous 1536B span, coalesced).
__global__ __launch_bounds__(256, 5)
void offset_gemm_kernel(const float* __restrict__ x,
                        const float* __restrict__ p_wTP,
                        const float* __restrict__ p_b,
                        float* __restrict__ offset,
                        unsigned short* __restrict__ x_t) {
    __shared__ float lds[288 * XR];          // 29952 B

    int bid = blockIdx.x;                    // 1152 = 2*24*24
    int j = bid % 24;
    int i = (bid / 24) % 24;
    int b = bid / 576;
    int sp0 = i * 576 + j * 24;
    int t = threadIdx.x;

    for (int it = t; it < 288 * 26; it += 256) {
        int row = it / 26, u = it % 26;
        int c = row / 9, dij = row % 9;
        int di = dij / 3, dj = dij % 3;
        int ii = i + di - 1, jj = j + dj - 1, kk = u - 1;
        bool v = ((unsigned)ii < (unsigned)DIM) && ((unsigned)jj < (unsigned)DIM) &&
                 ((unsigned)kk < (unsigned)DIM);
        lds[it] =
            v ? x[((size_t)(b * CC + c) * SP) + ii * 576 + jj * 24 + kk] : 0.f;
    }
    __syncthreads();

    // --- fused x_t emission from halo center plane (di=1, dj=1) ---
    {
        unsigned short* xtb = x_t + ((size_t)(b * SP + sp0)) * CC;
        for (int it = t; it < DIM * CC; it += 256) {     // 768 items
            int v = it >> 5, c = it & 31;
            xtb[it] = f2bf(lds[(c * 9 + 4) * XR + v + 1]);
        }
    }

    int w = t >> 6, l = t & 63;
    int mt = l / 3, vt = l % 3;
    bool act = (l < 63);
    if (mt > 20) mt = 20;                    // lane 63: duplicate, store-guarded

    float acc[4][8];
    #pragma unroll
    for (int a = 0; a < 4; ++a)
        #pragma unroll
        for (int e = 0; e < 8; ++e) acc[a][e] = 0.f;

    const float* wbase = p_wTP + (size_t)(w * 216) * MP + mt * 4;
    const float* xbase = lds + (w * 72) * XR + vt * 8;

    float4 pwA[3], pwB[3];
    #pragma unroll
    for (int dk = 0; dk < 3; ++dk)
        pwA[dk] = *(const float4*)(wbase + (size_t)dk * MP);

    #define FMA_BODY(PW, CDIJ)                                              \
        do {                                                                \
            const float* xr = xbase + (CDIJ) * XR;                          \
            float2 x0 = *(const float2*)(xr);                               \
            float2 x1 = *(const float2*)(xr + 2);                           \
            float2 x2 = *(const float2*)(xr + 4);                           \
            float2 x3 = *(const float2*)(xr + 6);                           \
            float2 x4 = *(const float2*)(xr + 8);                           \
            float xv[10] = { x0.x, x0.y, x1.x, x1.y, x2.x, x2.y,            \
                             x3.x, x3.y, x4.x, x4.y };                      \
            _Pragma("unroll")                                               \
            for (int dk = 0; dk < 3; ++dk) {                                \
                float4 wv = PW[dk];                                         \
                _Pragma("unroll")                                           \
                for (int e = 0; e < 8; ++e) {                               \
                    float xvv = xv[dk + e];                                 \
                    acc[0][e] += wv.x * xvv;                                \
                    acc[1][e] += wv.y * xvv;                                \
                    acc[2][e] += wv.z * xvv;                                \
                    acc[3][e] += wv.w * xvv;                                \
                }                                                           \
            }                                                               \
        } while (0)

    for (int cdij = 0; cdij < 72; cdij += 2) {
        {   // even: issue prefetch of cdij+1 into pwB, pin, compute cdij
            const float* wn = wbase + (size_t)((cdij + 1) * 3) * MP;
            #pragma unroll
            for (int dk = 0; dk < 3; ++dk)
                pwB[dk] = *(const float4*)(wn + (size_t)dk * MP);
            __builtin_amdgcn_sched_barrier(0);
            FMA_BODY(pwA, cdij);
        }
        {   // odd: prefetch cdij+2 into pwA; tail overreads land in the
            // adjacent conv_wbf ws region (valid memory, values unused).
            const float* wn = wbase + (size_t)((cdij + 2) * 3) * MP;
            #pragma unroll
            for (int dk = 0; dk < 3; ++dk)
                pwA[dk] = *(const float4*)(wn + (size_t)dk * MP);
            __builtin_amdgcn_sched_barrier(0);
            FMA_BODY(pwB, cdij + 1);
        }
    }
    #undef FMA_BODY
    __syncthreads();

    float* part = lds;                        // 2*84*24*4 = 16128 B
    if (act && w < 2) {
        #pragma unroll
        for (int a = 0; a < 4; ++a) {
            #pragma unroll
            for (int e2 = 0; e2 < 2; ++e2) {
                float4 pv = make_float4(acc[a][e2 * 4], acc[a][e2 * 4 + 1],
                                        acc[a][e2 * 4 + 2], acc[a][e2 * 4 + 3]);
                *(float4*)&part[((w * MP) + mt * 4 + a) * 24 + vt * 8 + e2 * 4] = pv;
            }
        }
    }
    __syncthreads();
    if (act && w >= 2) {
        #pragma unroll
        for (int a = 0; a < 4; ++a) {
            #pragma unroll
            for (int e2 = 0; e2 < 2; ++e2) {
                float* dst = &part[(((w - 2) * MP) + mt * 4 + a) * 24 + vt * 8 + e2 * 4];
                float4 pv = *(const float4*)dst;
                pv.x += acc[a][e2 * 4];     pv.y += acc[a][e2 * 4 + 1];
                pv.z += acc[a][e2 * 4 + 2]; pv.w += acc[a][e2 * 4 + 3];
                *(float4*)dst = pv;
            }
        }
    }
    __syncthreads();

    for (int it = t; it < M3 * 6; it += 256) {
        int m = it / 6, vq = it % 6;
        float4 p0 = *(const float4*)&part[(m) * 24 + vq * 4];
        float4 p1 = *(const float4*)&part[(MP + m) * 24 + vq * 4];
        float bias = p_b[m];
        float4 s = make_float4(p0.x + p1.x + bias, p0.y + p1.y + bias,
                               p0.z + p1.z + bias, p0.w + p1.w + bias);
        *(float4*)&offset[((size_t)(b * M3 + m)) * SP + sp0 + vq * 4] = s;
    }
}

// ------------- Kernel B: sample + project, 4-lane-per-point gather ----------
// Phase 2: 4 lanes per sample point, each owning an 8-channel slice ->
// contiguous quarters of each 64B corner line (16 L1 lines/wave-load vs 64).
// Measured ~39us (r15). VGPR floor >=64 at (256,4) (r12: 48 VGPR = +50us).
__global__ __launch_bounds__(256, 4)
void sample_gemm_kernel(const unsigned short* __restrict__ x_t,
                        const float* __restrict__ offset,
                        const unsigned short* __restrict__ conv_wbf,
                        float* __restrict__ out,     // [2, 64, SP]
                        float* __restrict__ p_out) { // [2, SP, 81]
    // region: col[12][896] bf16 (21504 B) then s_corner[8][324] u32 (10368 B)
    __shared__ __align__(16) unsigned char region[VBB * CPAD * 2 + 8 * NV * 4];
    unsigned short* col = (unsigned short*)region;
    unsigned* s_corner = (unsigned*)(region + VBB * CPAD * 2);

    int bid = blockIdx.x;                    // 2304 = 2*24*24*2
    int r = bid & 1;
    int j = (bid >> 1) % 24;
    int i = ((bid >> 1) / 24) % 24;
    int b = bid / 1152;
    int k0 = r * VBB;
    int sp0 = i * 576 + j * 24 + k0;
    int t = threadIdx.x;

    const unsigned short* xtb = x_t + (size_t)b * SP * CC;

    // --- phase 1: corners + p_out ---
    for (int it = t; it < NV; it += 256) {
        int v = it % VBB, n = it / VBB;
        int sp = sp0 + v;
        int k = k0 + v;

        int pnx = n / 9 - 1, pny = (n / 3) % 3 - 1, pnz = n % 3 - 1;
        float p0a[3] = { (float)(i + 1 + pnx),
                         (float)(j + 1 + pny),
                         (float)(k + 1 + pnz) };
        int ql[3], qh[3];
        float wl[3], wh[3];
        #pragma unroll
        for (int ax = 0; ax < 3; ++ax) {
            int m = ax * NPTS + n;
            float p = p0a[ax] + offset[((size_t)(b * M3 + m)) * SP + sp];
            float f = floorf(p);
            int qlo = (int)fminf(fmaxf(f,       0.f), 25.f);
            int qhi = (int)fminf(fmaxf(f + 1.f, 0.f), 25.f);
            bool oob = (p < 1.f) || (p > 24.f);
            float pa = oob ? f : p;
            float pm = fminf(fmaxf(pa, 0.f), 25.f);
            ql[ax] = qlo; qh[ax] = qhi;
            wl[ax] = 1.f + ((float)qlo - pm);
            wh[ax] = 1.f - ((float)qhi - pm);
            p_out[((size_t)(b * SP + sp)) * M3 + m] = pm;
        }

        #pragma unroll
        for (int cr = 0; cr < 8; ++cr) {
            int ii = ((cr & 4) ? qh[0] : ql[0]) - 1;
            int jj = ((cr & 2) ? qh[1] : ql[1]) - 1;
            int kk = ((cr & 1) ? qh[2] : ql[2]) - 1;
            bool valid = ((unsigned)ii < (unsigned)DIM) &&
                         ((unsigned)jj < (unsigned)DIM) &&
                         ((unsigned)kk < (unsigned)DIM);
            float cw = ((cr & 4) ? wh[0] : wl[0]) *
                       ((cr & 2) ? wh[1] : wl[1]) *
                       ((cr & 1) ? wh[2] : wl[2]);
            unsigned idx = (unsigned)(ii * 576 + jj * 24 + kk);
            s_corner[cr * NV + it] =
                valid ? ((idx << 16) | (unsigned)f2bf(cw)) : 0u;
        }
    }
    __syncthreads();

    // --- phase 2: gather; 4 lanes per item, lane owns 8-channel slice q ---
    for (int task = t; task < NV * 4; task += 256) {
        int item = task >> 2, q = task & 3;
        int v = item % VBB, n = item / VBB;

        const unsigned short* xq = xtb + q * 8;
        float acc[8];
        #pragma unroll
        for (int e = 0; e < 8; ++e) acc[e] = 0.f;

        #pragma unroll
        for (int cr = 0; cr < 8; ++cr) {
            unsigned u = s_corner[cr * NV + item];
            float wc = __builtin_bit_cast(float, u << 16);
            const unsigned* s = (const unsigned*)(xq + (size_t)(u >> 16) * CC);
            #pragma unroll
            for (int q2 = 0; q2 < 4; ++q2) {
                unsigned uu = s[q2];
                acc[2 * q2]     += wc * __builtin_bit_cast(float, uu << 16);
                acc[2 * q2 + 1] += wc * __builtin_bit_cast(float, uu & 0xFFFF0000u);
            }
        }

        short8 pk;
        #pragma unroll
        for (int e = 0; e < 8; ++e)
            pk[e] = (short)f2bf(acc[e]);
        int sv = (v & 7) << 3;
        *(short8*)&col[v * CPAD + ((n * 32 + q * 8) ^ sv)] = pk;
    }
    __syncthreads();

    // --- phase 3: MFMA GEMM 64 x 864 @ 864 x 12 ---
    {
        int mt = t >> 6;                      // wave -> M tile (16 rows)
        int l = t & 63;
        int lr = l & 15;                      // A row / B col (voxel)
        int g = l >> 4;
        int sv = (lr & 7) << 3;

        const short8* ap =
            (const short8*)(conv_wbf + ((size_t)(mt * 16 + lr)) * CN + g * 8);
        const unsigned short* bp = col + lr * CPAD;

        f32x4 acc = {0.f, 0.f, 0.f, 0.f};
        #pragma unroll 3
        for (int kb = 0; kb < CN / 32; ++kb) {
            short8 a = ap[kb * 4];
            short8 bb = *(const short8*)&bp[(kb * 32 + g * 8) ^ sv];
            acc = __builtin_amdgcn_mfma_f32_16x16x32_bf16(a, bb, acc, 0, 0, 0);
        }
        if (lr < VBB) {
            float* op = out + ((size_t)(b * OUTC + mt * 16 + g * 4)) * SP + sp0 + lr;
            #pragma unroll
            for (int rr = 0; rr < 4; ++rr)
                op[(size_t)rr * SP] = acc[rr];
        }
    }
}

extern "C" void kernel_launch(void* const* d_in, const int* in_sizes, int n_in,
                              void* d_out, int out_size, void* d_ws, size_t ws_size,
                              hipStream_t stream) {
    const float* x      = (const float*)d_in[0];
    const float* p_w    = (const float*)d_in[1];
    const float* p_b    = (const float*)d_in[2];
    const float* conv_w = (const float*)d_in[3];

    float* out_all = (float*)d_out;
    float* out_main = out_all;                               // [2,64,13824]
    float* p_out    = out_all + (size_t)BATCH * OUTC * SP;   // [2,13824,81]

    float* offset          = (float*)d_ws;                   // [2,81,13824]
    float* p_wTP           = offset + (size_t)BATCH * M3 * SP;
    unsigned short* conv_wbf = (unsigned short*)(p_wTP + (size_t)CN * MP);
    unsigned short* x_t    = conv_wbf + (size_t)CN * OUTC;   // [2,13824,32] bf16

    {
        int total = CN * MP;                                 // 72576 covers both
        prep_w_kernel<<<(total + 255) / 256, 256, 0, stream>>>(p_w, conv_w,
                                                               p_wTP, conv_wbf);
    }
    {
        int blocks = BATCH * 24 * 24;                        // 1152
        offset_gemm_kernel<<<blocks, 256, 0, stream>>>(x, p_wTP, p_b, offset,
                                                       x_t);
    }
    {
        int blocks = BATCH * 24 * 24 * 2;                    // 2304
        sample_gemm_kernel<<<blocks, 256, 0, stream>>>(x_t, offset, conv_wbf,
                                                       out_main, p_out);
    }
}